// Round 1
// baseline (661.192 us; speedup 1.0000x reference)
//
#include <hip/hip_runtime.h>
#include <math.h>

// CepstrumToImpulseResponse: h[0]=exp(c[0]); h[n] = (1/n) * sum_{m=1}^{min(n,99)} m*c[m]*h[n-m]
// B=65536, M=99 (CEP_ORDER), N=512 (IR_LENGTH). Output float32 [B, N].
//
// One thread per batch element. w[99] (weighted cepstrum) and h[99] (history
// shift register) live in VGPRs with fully static indexing. Time loop unrolled
// by U=7 (511 = 7*73) so the history shift (99 movs) is amortized over 7 steps.

#define BATCH     65536
#define CEP_M     99
#define IR_N      512
#define UNROLL_U  7
#define NGROUPS   73   // (IR_N - 1) / UNROLL_U == 511/7

__global__ __launch_bounds__(256, 1)
void cep2ir_kernel(const float* __restrict__ c, float* __restrict__ out) {
    const int b = blockIdx.x * 256 + threadIdx.x;
    const float* cb = c + (size_t)b * (CEP_M + 1);
    float* ob = out + (size_t)b * IR_N;

    // Load the 100 cepstral coeffs for this batch row (row base is 400 B -> 16B aligned).
    float cc[CEP_M + 1];
#pragma unroll
    for (int i = 0; i < (CEP_M + 1) / 4; ++i) {
        const float4 v = reinterpret_cast<const float4*>(cb)[i];
        cc[4 * i + 0] = v.x;
        cc[4 * i + 1] = v.y;
        cc[4 * i + 2] = v.z;
        cc[4 * i + 3] = v.w;
    }

    // w[m-1] = m * c[m], m = 1..99
    float w[CEP_M];
#pragma unroll
    for (int m = 1; m <= CEP_M; ++m) w[m - 1] = cc[m] * (float)m;

    const float h0 = expf(cc[0]);
    ob[0] = h0;

    // h[k] = h[n-1-k]; zeros stand in for negative time indices.
    float h[CEP_M];
#pragma unroll
    for (int i = 0; i < CEP_M; ++i) h[i] = 0.0f;
    h[0] = h0;

    float fn = 1.0f;  // float value of n for step j=0 of the current group
#pragma unroll 1
    for (int g = 0; g < NGROUPS; ++g) {
        float s[UNROLL_U];
        float* og = ob + 1 + g * UNROLL_U;
#pragma unroll
        for (int j = 0; j < UNROLL_U; ++j) {
            // h(n+j-m): for m <= j it's s[j-m] (this group), else h[m-1-j].
            float a[4] = {0.0f, 0.0f, 0.0f, 0.0f};
#pragma unroll
            for (int m = j + 1; m <= CEP_M; ++m)
                a[m & 3] += w[m - 1] * h[m - 1 - j];
#pragma unroll
            for (int m = 1; m <= j; ++m)
                a[m & 3] += w[m - 1] * s[j - m];
            const float t = (a[0] + a[1]) + (a[2] + a[3]);
            const float rn = __builtin_amdgcn_rcpf(fn + (float)j);
            s[j] = t * rn;
            og[j] = s[j];
        }
        // Shift history by U: h[k] <- h[k-U]; newest values in front.
#pragma unroll
        for (int k = CEP_M - 1; k >= UNROLL_U; --k) h[k] = h[k - UNROLL_U];
#pragma unroll
        for (int j = 0; j < UNROLL_U; ++j) h[UNROLL_U - 1 - j] = s[j];
        fn += (float)UNROLL_U;
    }
}

extern "C" void kernel_launch(void* const* d_in, const int* in_sizes, int n_in,
                              void* d_out, int out_size, void* d_ws, size_t ws_size,
                              hipStream_t stream) {
    const float* c = (const float*)d_in[0];
    float* out = (float*)d_out;
    cep2ir_kernel<<<BATCH / 256, 256, 0, stream>>>(c, out);
}